// Round 8
// baseline (136.744 us; speedup 1.0000x reference)
//
#include <hip/hip_runtime.h>
#include <hip/hip_bf16.h>

#define CIN 256
#define COUT 256
#define HH 32
#define WW 32
#define LL 4
#define NN 64   // B*L

typedef unsigned short u16;
typedef __attribute__((ext_vector_type(8))) short short8;   // 8 bf16 = one 16B unit
typedef __attribute__((ext_vector_type(4))) float f32x4;

typedef const __attribute__((address_space(1))) void gvoid_t;
typedef __attribute__((address_space(3))) void svoid_t;

static __device__ __forceinline__ u16 f2bf(float f) {
    __hip_bfloat16 h = __float2bfloat16(f);
    return *reinterpret_cast<u16*>(&h);
}
static __device__ __forceinline__ float bf2f(u16 b) {
    unsigned int u = ((unsigned int)b) << 16;
    return __uint_as_float(u);
}

// ---------------- Kernel 1 (fused): xb[n][ko][pos][8] = bf16(x), border zeros, pooled means
__global__ __launch_bounds__(256) void xb_prep_kernel(const float* __restrict__ x,
                                                      float* __restrict__ pooled,
                                                      u16* __restrict__ xb) {
    int blk = blockIdx.x;            // n*32 + ko
    int n = blk >> 5, ko = blk & 31;
    int tid = threadIdx.x;
    int lane = tid & 63, wave = tid >> 6;
    const float* xn = x + ((size_t)n * CIN + ko * 8) * (HH * WW);

    float4 v[8];
    float psum[8];
    #pragma unroll
    for (int ci = 0; ci < 8; ci++) {
        v[ci] = ((const float4*)(xn + ci * (HH * WW)))[tid];
        psum[ci] = v[ci].x + v[ci].y + v[ci].z + v[ci].w;
    }

    size_t base = ((size_t)n * 32 + ko) * (34 * 34);   // units
    #pragma unroll
    for (int k = 0; k < 4; k++) {
        int pos = tid * 4 + k;
        int h = pos >> 5, w = pos & 31;
        short8 u;
        #pragma unroll
        for (int ci = 0; ci < 8; ci++) {
            float f = (k == 0) ? v[ci].x : (k == 1) ? v[ci].y : (k == 2) ? v[ci].z : v[ci].w;
            u[ci] = (short)f2bf(f);
        }
        *(short8*)(xb + (base + (size_t)(h + 1) * 34 + (w + 1)) * 8) = u;
    }
    if (tid < 132) {
        int cell = tid;
        int hp, wp;
        if (cell < 34)       { hp = 0;              wp = cell; }
        else if (cell < 68)  { hp = 33;             wp = cell - 34; }
        else if (cell < 100) { hp = cell - 68 + 1;  wp = 0; }
        else                 { hp = cell - 100 + 1; wp = 33; }
        short8 z = (short8){0, 0, 0, 0, 0, 0, 0, 0};
        *(short8*)(xb + (base + (size_t)hp * 34 + wp) * 8) = z;
    }
    __shared__ float red[4][8];
    #pragma unroll
    for (int ci = 0; ci < 8; ci++) {
        float s = psum[ci];
        #pragma unroll
        for (int off = 32; off > 0; off >>= 1) s += __shfl_down(s, off, 64);
        if (lane == 0) red[wave][ci] = s;
    }
    __syncthreads();
    if (tid < 8) {
        pooled[n * CIN + ko * 8 + tid] =
            (red[0][tid] + red[1][tid] + red[2][tid] + red[3][tid]) * (1.0f / (HH * WW));
    }
}

// ---------------- Kernel 1b: twt[k][ci][co] = tconv_w[co][ci][k]  (for coalesced calib)
__global__ __launch_bounds__(256) void twt_kernel(const float* __restrict__ tconv_w,
                                                  float* __restrict__ twt) {
    int co = blockIdx.x;
    int tid = threadIdx.x;
    #pragma unroll
    for (int r = 0; r < 3; r++) {
        int idx = r * 256 + tid;           // 0..767
        int ci = idx / 3, k = idx - ci * 3;
        twt[((size_t)k * 256 + ci) * 256 + co] = tconv_w[(size_t)co * 768 + idx];
    }
}

// ---------------- Kernel 2: temporal calib + gate (coalesced via twt) ----------------
__global__ __launch_bounds__(256) void calib_fast_kernel(const float* __restrict__ pooled,
                                                         const float* __restrict__ twt,
                                                         const float* __restrict__ tconv_b,
                                                         const float* __restrict__ fc_w,
                                                         const float* __restrict__ fc_b,
                                                         float* __restrict__ scale,
                                                         float* __restrict__ gmul) {
    int n = blockIdx.x;
    int b = n / LL, t = n % LL;
    int i0 = max(t - 2, 0), i1 = max(t - 1, 0), i2 = t;
    __shared__ float p[3][CIN];
    int tid = threadIdx.x;                 // = co for calib, = ci for gate
    p[0][tid] = pooled[(b * LL + i0) * CIN + tid];
    p[1][tid] = pooled[(b * LL + i1) * CIN + tid];
    p[2][tid] = pooled[(b * LL + i2) * CIN + tid];
    __syncthreads();
    float acc = 0.f;
    #pragma unroll 4
    for (int ci = 0; ci < CIN; ci++) {
        acc += p[0][ci] * twt[(size_t)(0 * 256 + ci) * 256 + tid]
             + p[1][ci] * twt[(size_t)(1 * 256 + ci) * 256 + tid]
             + p[2][ci] * twt[(size_t)(2 * 256 + ci) * 256 + tid];
    }
    scale[n * CIN + tid] = acc + tconv_b[tid] + 1.0f;
    const float* fw = fc_w + tid * 3;
    float g = p[0][tid] * fw[0] + p[1][tid] * fw[1] + p[2][tid] * fw[2];
    #pragma unroll
    for (int off = 32; off > 0; off >>= 1) g += __shfl_down(g, off, 64);
    __shared__ float gw[4];
    if ((tid & 63) == 0) gw[tid >> 6] = g;
    __syncthreads();
    if (tid == 0) gmul[n] = gw[0] + gw[1] + gw[2] + gw[3] + fc_b[0] + 1.0f;
}

// ---------------- Kernel 3: wb2[tap][ko(32)][co(256)][8] (unscaled bf16 weights)
__global__ __launch_bounds__(256) void wprep_kernel(const float* __restrict__ weight,
                                                    u16* __restrict__ wb) {
    int co = blockIdx.x;
    int ci = threadIdx.x;
    #pragma unroll
    for (int k = 0; k < 9; k++) {
        u16 v = f2bf(weight[((size_t)co * CIN + ci) * 9 + k]);
        size_t unit = ((size_t)k * 32 + (ci >> 3)) * COUT + co;
        wb[unit * 8 + (ci & 7)] = v;
    }
}

// ---------------- Kernel 4: MFMA implicit-GEMM conv ----------------
// Block = (n, cog of 64 co, pg of 16 rows). 4 waves; wave = 64co x 128pos (4 rows x 32 cols).
// A read DIRECT from L2 (wb, 1.2 MB, XCD-resident) with reg scale: af = bf16(bf16(w)*s[ci]).
// B only in LDS, double-buffered (2 x 2496 units = 79,872 B), counted vmcnt(9) pipeline:
//   barrier -> issue B(kc+1) -> vmcnt(9) -> barrier -> compute(kc)  [loads in flight across barriers]
#define BBUF 2496
#define BSTR 614   // k8 stride in units: 614*16 B == 96 mod 128 -> l4 groups bank-spread

__global__ __launch_bounds__(256, 2) void conv_mfma_kernel(
    const u16* __restrict__ xb, const u16* __restrict__ wb,
    const float* __restrict__ scale,
    const float* __restrict__ bias, const float* __restrict__ gmul,
    float* __restrict__ out) {
    // XCD-aware swizzle: 512 blocks, 8 XCDs -> all 8 blocks of one n on one XCD
    int blk = (blockIdx.x & 7) * 64 + (blockIdx.x >> 3);
    int n = blk >> 3, cog = (blk >> 1) & 3, pg = blk & 1;
    int r0 = pg * 16;
    int tid = threadIdx.x;
    int lane = tid & 63, wave = tid >> 6;
    int l15 = lane & 15, l4 = lane >> 4;
    int w4 = wave * 4;

    __shared__ short8 Blds[2 * BBUF];   // 79,872 B -> 2 blocks/CU

    f32x4 acc[4][4][2];
    #pragma unroll
    for (int m = 0; m < 4; m++)
        #pragma unroll
        for (int r = 0; r < 4; r++)
            #pragma unroll
            for (int ch = 0; ch < 2; ch++) acc[m][r][ch] = (f32x4){0.f, 0.f, 0.f, 0.f};

    // kc-invariant B staging offsets (dest linear; src clamped into valid region)
    int b_off[10];
    #pragma unroll
    for (int r = 0; r < 10; r++) {
        int u = r * 256 + tid;
        int ue = u < 2455 ? u : 2455;
        int k8 = ue / BSTR;
        int rem = ue - k8 * BSTR;
        if (rem > 611) rem = 611;
        b_off[r] = k8 * 1156 + rem;
    }
    int b_base0 = n * 36992 + r0 * 34;

    #define STAGE_B(buf, kc_) do {                                                       \
        _Pragma("unroll")                                                                \
        for (int r = 0; r < 10; r++) {                                                   \
            if (!(r == 9 && wave == 3)) {                                                \
                size_t gu = (size_t)(b_base0 + (kc_) * 4624 + b_off[r]);                 \
                __builtin_amdgcn_global_load_lds((gvoid_t*)(xb + gu * 8),                \
                    (svoid_t*)&Blds[(buf) * BBUF + r * 256 + wave * 64], 16, 0, 0);      \
            }                                                                            \
        }                                                                                \
    } while (0)

    STAGE_B(0, 0);

    const u16* wbl = wb + (size_t)(cog * 64 + l15) * 8;   // + (tap*8192 + kc*1024 + l4*256 + m*16)*8

    for (int kc = 0; kc < 8; kc++) {
        __builtin_amdgcn_s_barrier();          // all waves done reading buf^1
        if (kc < 7) STAGE_B((kc + 1) & 1, kc + 1);
        asm volatile("s_waitcnt vmcnt(9)" ::: "memory");   // current buf landed; next stays in flight
        __builtin_amdgcn_sched_barrier(0);
        __builtin_amdgcn_s_barrier();

        const short8* Bb = &Blds[(kc & 1) * BBUF];
        // per-lane scale vector for ci = kc*32 + l4*8 + e
        f32x4 s0 = *(const f32x4*)(scale + n * 256 + kc * 32 + l4 * 8);
        f32x4 s1 = *(const f32x4*)(scale + n * 256 + kc * 32 + l4 * 8 + 4);

        #pragma unroll
        for (int dw = 0; dw < 3; dw++) {
            short8 bfr[6][2];
            #pragma unroll
            for (int j = 0; j < 6; j++)
                #pragma unroll
                for (int ch = 0; ch < 2; ch++) {
                    int u = l4 * BSTR + (w4 + j) * 34 + ch * 16 + l15 + dw;
                    bfr[j][ch] = Bb[u];
                }
            #pragma unroll
            for (int dh = 0; dh < 3; dh++) {
                int tap = dh * 3 + dw;
                #pragma unroll
                for (int m = 0; m < 4; m++) {
                    short8 aw = *(const short8*)(wbl + ((size_t)tap * 8192 + kc * 1024 + l4 * 256 + m * 16) * 8);
                    short8 af;
                    #pragma unroll
                    for (int e = 0; e < 8; e++) {
                        float s = (e < 4) ? s0[e] : s1[e - 4];
                        af[e] = (short)f2bf(bf2f((u16)aw[e]) * s);
                    }
                    #pragma unroll
                    for (int r = 0; r < 4; r++)
                        #pragma unroll
                        for (int ch = 0; ch < 2; ch++)
                            acc[m][r][ch] = __builtin_amdgcn_mfma_f32_16x16x32_bf16(
                                af, bfr[r + dh][ch], acc[m][r][ch], 0, 0, 0);
                }
            }
        }
    }
    #undef STAGE_B

    // ---- epilogue: D row=(l>>4)*4+j -> co, col=l&15 -> pos
    float gm = gmul[n];
    #pragma unroll
    for (int m = 0; m < 4; m++) {
        #pragma unroll
        for (int r = 0; r < 4; r++) {
            int orow = r0 + w4 + r;
            #pragma unroll
            for (int ch = 0; ch < 2; ch++) {
                #pragma unroll
                for (int j = 0; j < 4; j++) {
                    int co = cog * 64 + m * 16 + l4 * 4 + j;
                    out[(((size_t)n * COUT + co) * HH + orow) * WW + ch * 16 + l15] =
                        acc[m][r][ch][j] + bias[co] * gm;
                }
            }
        }
    }
}

// ---------------- Fallback path (ws too small): pool + calib + fp32 direct conv ----------------
__global__ __launch_bounds__(256) void pool_kernel(const float* __restrict__ x,
                                                   float* __restrict__ pooled) {
    int blk = blockIdx.x;
    const float* src = x + (size_t)blk * (HH * WW);
    int tid = threadIdx.x;
    float4 v = ((const float4*)src)[tid];
    float s = v.x + v.y + v.z + v.w;
    #pragma unroll
    for (int off = 32; off > 0; off >>= 1) s += __shfl_down(s, off, 64);
    __shared__ float ws[4];
    if ((tid & 63) == 0) ws[tid >> 6] = s;
    __syncthreads();
    if (tid == 0) pooled[blk] = (ws[0] + ws[1] + ws[2] + ws[3]) * (1.0f / (HH * WW));
}

__global__ __launch_bounds__(256) void calib_kernel(const float* __restrict__ pooled,
                                                    const float* __restrict__ tconv_w,
                                                    const float* __restrict__ tconv_b,
                                                    const float* __restrict__ fc_w,
                                                    const float* __restrict__ fc_b,
                                                    float* __restrict__ scale,
                                                    float* __restrict__ gmul) {
    int n = blockIdx.x;
    int b = n / LL, t = n % LL;
    int i0 = max(t - 2, 0), i1 = max(t - 1, 0), i2 = t;
    __shared__ float p[3][CIN];
    int tid = threadIdx.x;
    p[0][tid] = pooled[(b * LL + i0) * CIN + tid];
    p[1][tid] = pooled[(b * LL + i1) * CIN + tid];
    p[2][tid] = pooled[(b * LL + i2) * CIN + tid];
    __syncthreads();
    float acc = 0.f;
    for (int ci = 0; ci < CIN; ci++) {
        const float* w = tconv_w + ((size_t)tid * CIN + ci) * 3;
        acc += p[0][ci] * w[0] + p[1][ci] * w[1] + p[2][ci] * w[2];
    }
    scale[n * CIN + tid] = acc + tconv_b[tid] + 1.0f;
    const float* fw = fc_w + tid * 3;
    float g = p[0][tid] * fw[0] + p[1][tid] * fw[1] + p[2][tid] * fw[2];
    #pragma unroll
    for (int off = 32; off > 0; off >>= 1) g += __shfl_down(g, off, 64);
    __shared__ float gw[4];
    if ((tid & 63) == 0) gw[tid >> 6] = g;
    __syncthreads();
    if (tid == 0) gmul[n] = gw[0] + gw[1] + gw[2] + gw[3] + fc_b[0] + 1.0f;
}

__global__ __launch_bounds__(256) void conv_kernel(const float* __restrict__ x,
                                                   const float* __restrict__ weight,
                                                   const float* __restrict__ bias,
                                                   const float* __restrict__ scale,
                                                   const float* __restrict__ gmul,
                                                   float* __restrict__ out) {
    int blk = blockIdx.x;
    int n   = blk >> 5;
    int cog = (blk >> 3) & 3;
    int rg  = blk & 7;
    int co_base  = cog * 64;
    int row_base = rg * 4;
    int tid = threadIdx.x;
    int c   = tid & 31;
    int sub = tid >> 5;

    __shared__ float xin[6][34];
    __shared__ float wsh[9][65];

    float acc[8][4];
    #pragma unroll
    for (int j = 0; j < 8; j++)
        #pragma unroll
        for (int g = 0; g < 4; g++) acc[j][g] = 0.f;

    const float* xn = x + (size_t)n * CIN * HH * WW;

    for (int ci = 0; ci < CIN; ci++) {
        if (tid < 204) {
            float s = scale[n * CIN + ci];
            int lr = tid / 34, lc = tid % 34;
            int gr = row_base - 1 + lr, gc = lc - 1;
            float v = 0.f;
            if (gr >= 0 && gr < HH && gc >= 0 && gc < WW)
                v = xn[(size_t)ci * (HH * WW) + gr * WW + gc] * s;
            xin[lr][lc] = v;
        }
        for (int idx = tid; idx < 576; idx += 256) {
            int co = idx / 9, k = idx % 9;
            wsh[k][co] = weight[(size_t)(co_base + co) * (CIN * 9) + ci * 9 + k];
        }
        __syncthreads();
        float xr[6][3];
        #pragma unroll
        for (int r = 0; r < 6; r++)
            #pragma unroll
            for (int kw = 0; kw < 3; kw++) xr[r][kw] = xin[r][c + kw];
        #pragma unroll
        for (int j = 0; j < 8; j++) {
            float wv[9];
            #pragma unroll
            for (int k = 0; k < 9; k++) wv[k] = wsh[k][sub * 8 + j];
            #pragma unroll
            for (int g = 0; g < 4; g++)
                #pragma unroll
                for (int kh = 0; kh < 3; kh++)
                    #pragma unroll
                    for (int kw = 0; kw < 3; kw++)
                        acc[j][g] += xr[g + kh][kw] * wv[kh * 3 + kw];
        }
        __syncthreads();
    }
    float gm = gmul[n];
    #pragma unroll
    for (int j = 0; j < 8; j++) {
        int co = co_base + sub * 8 + j;
        float fb = bias[co] * gm;
        #pragma unroll
        for (int g = 0; g < 4; g++)
            out[(((size_t)n * COUT + co) * HH + (row_base + g)) * WW + c] = acc[j][g] + fb;
    }
}

extern "C" void kernel_launch(void* const* d_in, const int* in_sizes, int n_in,
                              void* d_out, int out_size, void* d_ws, size_t ws_size,
                              hipStream_t stream) {
    const float* x       = (const float*)d_in[0];
    const float* weight  = (const float*)d_in[1];
    const float* bias    = (const float*)d_in[2];
    const float* tconv_w = (const float*)d_in[3];
    const float* tconv_b = (const float*)d_in[4];
    const float* fc_w    = (const float*)d_in[5];
    const float* fc_b    = (const float*)d_in[6];
    float* out = (float*)d_out;

    char* wsb = (char*)d_ws;
    float* pooled = (float*)wsb;                       // 16384 f
    float* scale  = pooled + NN * CIN;                 // 16384 f
    float* gmul   = scale + NN * CIN;                  // 64 f
    const size_t XB_OFF = 131328;                      // bytes, 16-aligned
    const size_t XB_BYTES = (size_t)NN * 32 * 34 * 34 * 8 * 2;   // 37,879,808
    const size_t WB_OFF = XB_OFF + XB_BYTES;
    const size_t WB_BYTES = (size_t)9 * 32 * COUT * 8 * 2;       // 1,179,648
    const size_t TWT_OFF = WB_OFF + WB_BYTES;
    const size_t TWT_BYTES = (size_t)3 * 256 * 256 * 4;          // 786,432
    u16* xb = (u16*)(wsb + XB_OFF);
    u16* wb = (u16*)(wsb + WB_OFF);
    float* twt = (float*)(wsb + TWT_OFF);

    if (ws_size >= TWT_OFF + TWT_BYTES) {
        xb_prep_kernel<<<NN * 32, 256, 0, stream>>>(x, pooled, xb);
        twt_kernel<<<COUT, 256, 0, stream>>>(tconv_w, twt);
        calib_fast_kernel<<<NN, 256, 0, stream>>>(pooled, twt, tconv_b, fc_w, fc_b, scale, gmul);
        wprep_kernel<<<COUT, 256, 0, stream>>>(weight, wb);
        conv_mfma_kernel<<<NN * 4 * 2, 256, 0, stream>>>(xb, wb, scale, bias, gmul, out);
    } else {
        pool_kernel<<<NN * CIN, 256, 0, stream>>>(x, pooled);
        calib_kernel<<<NN, 256, 0, stream>>>(pooled, tconv_w, tconv_b, fc_w, fc_b, scale, gmul);
        conv_kernel<<<NN * 32, 256, 0, stream>>>(x, weight, bias, scale, gmul, out);
    }
}

// Round 9
// 125.240 us; speedup vs baseline: 1.0919x; 1.0919x over previous
//
#include <hip/hip_runtime.h>
#include <hip/hip_bf16.h>

#define CIN 256
#define COUT 256
#define HH 32
#define WW 32
#define LL 4
#define NN 64   // B*L

typedef unsigned short u16;
typedef __attribute__((ext_vector_type(8))) short short8;   // 8 bf16 = one 16B unit
typedef __attribute__((ext_vector_type(4))) float f32x4;

typedef const __attribute__((address_space(1))) void gvoid_t;
typedef __attribute__((address_space(3))) void svoid_t;

static __device__ __forceinline__ u16 f2bf(float f) {
    __hip_bfloat16 h = __float2bfloat16(f);
    return *reinterpret_cast<u16*>(&h);
}
static __device__ __forceinline__ float bf2f(u16 b) {
    unsigned int u = ((unsigned int)b) << 16;
    return __uint_as_float(u);
}

// ---------------- Kernel 1 (fused): xb[n][ko][pos][8] = bf16(x), border zeros, pooled means
__global__ __launch_bounds__(256) void xb_prep_kernel(const float* __restrict__ x,
                                                      float* __restrict__ pooled,
                                                      u16* __restrict__ xb) {
    int blk = blockIdx.x;            // n*32 + ko
    int n = blk >> 5, ko = blk & 31;
    int tid = threadIdx.x;
    int lane = tid & 63, wave = tid >> 6;
    const float* xn = x + ((size_t)n * CIN + ko * 8) * (HH * WW);

    float4 v[8];
    float psum[8];
    #pragma unroll
    for (int ci = 0; ci < 8; ci++) {
        v[ci] = ((const float4*)(xn + ci * (HH * WW)))[tid];
        psum[ci] = v[ci].x + v[ci].y + v[ci].z + v[ci].w;
    }

    size_t base = ((size_t)n * 32 + ko) * (34 * 34);   // units
    #pragma unroll
    for (int k = 0; k < 4; k++) {
        int pos = tid * 4 + k;
        int h = pos >> 5, w = pos & 31;
        short8 u;
        #pragma unroll
        for (int ci = 0; ci < 8; ci++) {
            float f = (k == 0) ? v[ci].x : (k == 1) ? v[ci].y : (k == 2) ? v[ci].z : v[ci].w;
            u[ci] = (short)f2bf(f);
        }
        *(short8*)(xb + (base + (size_t)(h + 1) * 34 + (w + 1)) * 8) = u;
    }
    if (tid < 132) {
        int cell = tid;
        int hp, wp;
        if (cell < 34)       { hp = 0;              wp = cell; }
        else if (cell < 68)  { hp = 33;             wp = cell - 34; }
        else if (cell < 100) { hp = cell - 68 + 1;  wp = 0; }
        else                 { hp = cell - 100 + 1; wp = 33; }
        short8 z = (short8){0, 0, 0, 0, 0, 0, 0, 0};
        *(short8*)(xb + (base + (size_t)hp * 34 + wp) * 8) = z;
    }
    __shared__ float red[4][8];
    #pragma unroll
    for (int ci = 0; ci < 8; ci++) {
        float s = psum[ci];
        #pragma unroll
        for (int off = 32; off > 0; off >>= 1) s += __shfl_down(s, off, 64);
        if (lane == 0) red[wave][ci] = s;
    }
    __syncthreads();
    if (tid < 8) {
        pooled[n * CIN + ko * 8 + tid] =
            (red[0][tid] + red[1][tid] + red[2][tid] + red[3][tid]) * (1.0f / (HH * WW));
    }
}

// ---------------- Kernel 1b (merged): wb2[tap][ko][co][8] bf16 weights + twt[k][ci][co]
__global__ __launch_bounds__(256) void wtprep_kernel(const float* __restrict__ weight,
                                                     const float* __restrict__ tconv_w,
                                                     u16* __restrict__ wb,
                                                     float* __restrict__ twt) {
    int tid = threadIdx.x;
    if (blockIdx.x < 256) {
        int co = blockIdx.x;
        int ci = tid;
        #pragma unroll
        for (int k = 0; k < 9; k++) {
            u16 v = f2bf(weight[((size_t)co * CIN + ci) * 9 + k]);
            size_t unit = ((size_t)k * 32 + (ci >> 3)) * COUT + co;
            wb[unit * 8 + (ci & 7)] = v;
        }
    } else {
        int co = blockIdx.x - 256;
        #pragma unroll
        for (int r = 0; r < 3; r++) {
            int idx = r * 256 + tid;           // 0..767
            int ci = idx / 3, k = idx - ci * 3;
            twt[((size_t)k * 256 + ci) * 256 + co] = tconv_w[(size_t)co * 768 + idx];
        }
    }
}

// ---------------- Kernel 2: temporal calib + gate (coalesced via twt) ----------------
__global__ __launch_bounds__(256) void calib_fast_kernel(const float* __restrict__ pooled,
                                                         const float* __restrict__ twt,
                                                         const float* __restrict__ tconv_b,
                                                         const float* __restrict__ fc_w,
                                                         const float* __restrict__ fc_b,
                                                         float* __restrict__ scale,
                                                         float* __restrict__ gmul) {
    int n = blockIdx.x;
    int b = n / LL, t = n % LL;
    int i0 = max(t - 2, 0), i1 = max(t - 1, 0), i2 = t;
    __shared__ float p[3][CIN];
    int tid = threadIdx.x;
    p[0][tid] = pooled[(b * LL + i0) * CIN + tid];
    p[1][tid] = pooled[(b * LL + i1) * CIN + tid];
    p[2][tid] = pooled[(b * LL + i2) * CIN + tid];
    __syncthreads();
    float acc = 0.f;
    #pragma unroll 4
    for (int ci = 0; ci < CIN; ci++) {
        acc += p[0][ci] * twt[(size_t)(0 * 256 + ci) * 256 + tid]
             + p[1][ci] * twt[(size_t)(1 * 256 + ci) * 256 + tid]
             + p[2][ci] * twt[(size_t)(2 * 256 + ci) * 256 + tid];
    }
    scale[n * CIN + tid] = acc + tconv_b[tid] + 1.0f;
    const float* fw = fc_w + tid * 3;
    float g = p[0][tid] * fw[0] + p[1][tid] * fw[1] + p[2][tid] * fw[2];
    #pragma unroll
    for (int off = 32; off > 0; off >>= 1) g += __shfl_down(g, off, 64);
    __shared__ float gw[4];
    if ((tid & 63) == 0) gw[tid >> 6] = g;
    __syncthreads();
    if (tid == 0) gmul[n] = gw[0] + gw[1] + gw[2] + gw[3] + fc_b[0] + 1.0f;
}

// ---------------- Kernel 4: MFMA implicit-GEMM conv, counted-vmcnt pipeline ----------------
// Block = (n, cog of 64 co, pg of 8 rows). 4 waves; wave = 64co x 64pos (2 rows x 32 cols).
// LDS: A single buf 2304 units (XOR-swizzled, stride 64) + B dbuf 2x1408 units = 81,920 B
//   -> exactly 2 blocks/CU.
// Per kc: barrier -> issue B(kc+1)->buf^1 -> convert A(kc) from prefetched regs + ds_write
//   -> issue A(kc+1) reg loads -> vmcnt(15/14) lgkm(0) -> barrier -> MFMA(kc).
// In-order vmcnt retirement: waiting on A(kc) (issued after B(kc)) implies B(kc) landed.
#define AU 2304
#define BB 1408   // 1360 used + 48 pad (chunk-21 clamp writes land in pad)

__global__ __launch_bounds__(256, 2) void conv_mfma_kernel(
    const u16* __restrict__ xb, const u16* __restrict__ wb,
    const float* __restrict__ scale,
    const float* __restrict__ bias, const float* __restrict__ gmul,
    float* __restrict__ out) {
    // XCD swizzle: 1024 blocks, 8 XCDs -> 128 consecutive logical blocks (8 n's) per XCD
    int blk = (blockIdx.x & 7) * 128 + (blockIdx.x >> 3);
    int n = blk >> 4, cog = (blk >> 2) & 3, pg = blk & 3;
    int r0 = pg * 8;
    int tid = threadIdx.x;
    int lane = tid & 63, wave = tid >> 6;
    int l15 = lane & 15, l4 = lane >> 4;
    int w2 = wave * 2;

    __shared__ short8 smem[5120];       // 81,920 B exactly
    short8* As = smem;
    short8* Bs = smem + AU;

    f32x4 acc[4][2][2];
    #pragma unroll
    for (int m = 0; m < 4; m++)
        #pragma unroll
        for (int r = 0; r < 2; r++)
            #pragma unroll
            for (int ch = 0; ch < 2; ch++) acc[m][r][ch] = (f32x4){0.f, 0.f, 0.f, 0.f};

    // B staging: 22 chunks of 64 units; chunk c = r*4+wave; dest = c*64 (+lane*16 by HW)
    int bsrc[6];
    #pragma unroll
    for (int r = 0; r < 6; r++) {
        int c = r * 4 + wave;
        int u = c * 64 + lane;
        if (u > 1359) u = 1359;
        int k8 = u / 340;
        bsrc[r] = u + k8 * 816;          // slab unit = k8*1156 + row*34 + col
    }
    int b_base0 = n * 36992 + r0 * 34;

    #define STAGE_B(buf, kc_) do {                                                     \
        _Pragma("unroll")                                                              \
        for (int r = 0; r < 6; r++) {                                                  \
            int c = r * 4 + wave;                                                      \
            if (c < 22) {                                                              \
                size_t gu = (size_t)(b_base0 + (kc_) * 4624 + bsrc[r]);                \
                __builtin_amdgcn_global_load_lds((gvoid_t*)(xb + gu * 8),              \
                    (svoid_t*)&Bs[(buf) * BB + c * 64], 16, 0, 0);                     \
            }                                                                          \
        }                                                                              \
    } while (0)

    #define LOAD_A(dst, kc_) do {                                                      \
        _Pragma("unroll")                                                              \
        for (int r = 0; r < 9; r++) {                                                  \
            size_t gu = (size_t)(r * 8192 + (kc_) * 1024 + wave * 256 + cog * 64 + lane); \
            dst[r] = *(const short8*)(wb + gu * 8);                                    \
        }                                                                              \
    } while (0)

    #define A_WRITE(src, kc_) do {                                                     \
        f32x4 s0 = *(const f32x4*)(scale + n * 256 + (kc_) * 32 + wave * 8);           \
        f32x4 s1 = *(const f32x4*)(scale + n * 256 + (kc_) * 32 + wave * 8 + 4);       \
        _Pragma("unroll")                                                              \
        for (int r = 0; r < 9; r++) {                                                  \
            int row = r * 4 + wave;                                                    \
            short8 o;                                                                  \
            _Pragma("unroll")                                                          \
            for (int e = 0; e < 8; e++) {                                              \
                float s = (e < 4) ? s0[e] : s1[e - 4];                                 \
                o[e] = (short)f2bf(bf2f((u16)src[r][e]) * s);                          \
            }                                                                          \
            *(short8*)((char*)As + (((row * 64 + lane) * 16) ^ ((row & 7) << 4))) = o; \
        }                                                                              \
    } while (0)

    #define COMPUTE(buf) do {                                                          \
        const short8* Bb = Bs + (buf) * BB;                                            \
        _Pragma("unroll")                                                              \
        for (int dw = 0; dw < 3; dw++) {                                               \
            short8 bfr[4][2];                                                          \
            _Pragma("unroll")                                                          \
            for (int j = 0; j < 4; j++)                                                \
                _Pragma("unroll")                                                      \
                for (int ch = 0; ch < 2; ch++) {                                       \
                    int u = l4 * 340 + (w2 + j) * 34 + ch * 16 + l15 + dw;             \
                    bfr[j][ch] = Bb[u];                                                \
                }                                                                      \
            _Pragma("unroll")                                                          \
            for (int dh = 0; dh < 3; dh++) {                                           \
                int tap = dh * 3 + dw;                                                 \
                _Pragma("unroll")                                                      \
                for (int m = 0; m < 4; m++) {                                          \
                    int row = tap * 4 + l4;                                            \
                    short8 af = *(const short8*)((const char*)As +                     \
                        (((row * 64 + m * 16 + l15) * 16) ^ ((row & 7) << 4)));        \
                    _Pragma("unroll")                                                  \
                    for (int r = 0; r < 2; r++)                                        \
                        _Pragma("unroll")                                              \
                        for (int ch = 0; ch < 2; ch++)                                 \
                            acc[m][r][ch] = __builtin_amdgcn_mfma_f32_16x16x32_bf16(   \
                                af, bfr[r + dh][ch], acc[m][r][ch], 0, 0, 0);          \
                }                                                                      \
            }                                                                          \
        }                                                                              \
    } while (0)

    #define ITER(kc_, CUR, NXT) do {                                                   \
        __builtin_amdgcn_s_barrier();                                                  \
        if ((kc_) < 7) STAGE_B(((kc_) + 1) & 1, (kc_) + 1);                            \
        A_WRITE(CUR, kc_);                                                             \
        if ((kc_) < 7) LOAD_A(NXT, (kc_) + 1);                                         \
        if ((kc_) < 7) {                                                               \
            if (wave < 2) asm volatile("s_waitcnt vmcnt(15)" ::: "memory");            \
            else          asm volatile("s_waitcnt vmcnt(14)" ::: "memory");            \
        } else {                                                                       \
            asm volatile("s_waitcnt vmcnt(0)" ::: "memory");                           \
        }                                                                              \
        asm volatile("s_waitcnt lgkmcnt(0)" ::: "memory");                             \
        __builtin_amdgcn_sched_barrier(0);                                             \
        __builtin_amdgcn_s_barrier();                                                  \
        __builtin_amdgcn_sched_barrier(0);                                             \
        __builtin_amdgcn_s_setprio(1);                                                 \
        COMPUTE((kc_) & 1);                                                            \
        __builtin_amdgcn_s_setprio(0);                                                 \
    } while (0)

    short8 wva[9], wvb[9];
    LOAD_A(wva, 0);
    STAGE_B(0, 0);

    ITER(0, wva, wvb);
    ITER(1, wvb, wva);
    ITER(2, wva, wvb);
    ITER(3, wvb, wva);
    ITER(4, wva, wvb);
    ITER(5, wvb, wva);
    ITER(6, wva, wvb);
    ITER(7, wvb, wva);

    #undef ITER
    #undef COMPUTE
    #undef A_WRITE
    #undef LOAD_A
    #undef STAGE_B

    // ---- epilogue: D row=(l>>4)*4+j -> co, col=l&15 -> pos
    float gm = gmul[n];
    #pragma unroll
    for (int m = 0; m < 4; m++) {
        #pragma unroll
        for (int r = 0; r < 2; r++) {
            int orow = r0 + w2 + r;
            #pragma unroll
            for (int ch = 0; ch < 2; ch++) {
                #pragma unroll
                for (int j = 0; j < 4; j++) {
                    int co = cog * 64 + m * 16 + l4 * 4 + j;
                    out[(((size_t)n * COUT + co) * HH + orow) * WW + ch * 16 + l15] =
                        acc[m][r][ch][j] + bias[co] * gm;
                }
            }
        }
    }
}

// ---------------- Fallback path (ws too small): pool + calib + fp32 direct conv ----------------
__global__ __launch_bounds__(256) void pool_kernel(const float* __restrict__ x,
                                                   float* __restrict__ pooled) {
    int blk = blockIdx.x;
    const float* src = x + (size_t)blk * (HH * WW);
    int tid = threadIdx.x;
    float4 v = ((const float4*)src)[tid];
    float s = v.x + v.y + v.z + v.w;
    #pragma unroll
    for (int off = 32; off > 0; off >>= 1) s += __shfl_down(s, off, 64);
    __shared__ float ws[4];
    if ((tid & 63) == 0) ws[tid >> 6] = s;
    __syncthreads();
    if (tid == 0) pooled[blk] = (ws[0] + ws[1] + ws[2] + ws[3]) * (1.0f / (HH * WW));
}

__global__ __launch_bounds__(256) void calib_kernel(const float* __restrict__ pooled,
                                                    const float* __restrict__ tconv_w,
                                                    const float* __restrict__ tconv_b,
                                                    const float* __restrict__ fc_w,
                                                    const float* __restrict__ fc_b,
                                                    float* __restrict__ scale,
                                                    float* __restrict__ gmul) {
    int n = blockIdx.x;
    int b = n / LL, t = n % LL;
    int i0 = max(t - 2, 0), i1 = max(t - 1, 0), i2 = t;
    __shared__ float p[3][CIN];
    int tid = threadIdx.x;
    p[0][tid] = pooled[(b * LL + i0) * CIN + tid];
    p[1][tid] = pooled[(b * LL + i1) * CIN + tid];
    p[2][tid] = pooled[(b * LL + i2) * CIN + tid];
    __syncthreads();
    float acc = 0.f;
    for (int ci = 0; ci < CIN; ci++) {
        const float* w = tconv_w + ((size_t)tid * CIN + ci) * 3;
        acc += p[0][ci] * w[0] + p[1][ci] * w[1] + p[2][ci] * w[2];
    }
    scale[n * CIN + tid] = acc + tconv_b[tid] + 1.0f;
    const float* fw = fc_w + tid * 3;
    float g = p[0][tid] * fw[0] + p[1][tid] * fw[1] + p[2][tid] * fw[2];
    #pragma unroll
    for (int off = 32; off > 0; off >>= 1) g += __shfl_down(g, off, 64);
    __shared__ float gw[4];
    if ((tid & 63) == 0) gw[tid >> 6] = g;
    __syncthreads();
    if (tid == 0) gmul[n] = gw[0] + gw[1] + gw[2] + gw[3] + fc_b[0] + 1.0f;
}

__global__ __launch_bounds__(256) void conv_kernel(const float* __restrict__ x,
                                                   const float* __restrict__ weight,
                                                   const float* __restrict__ bias,
                                                   const float* __restrict__ scale,
                                                   const float* __restrict__ gmul,
                                                   float* __restrict__ out) {
    int blk = blockIdx.x;
    int n   = blk >> 5;
    int cog = (blk >> 3) & 3;
    int rg  = blk & 7;
    int co_base  = cog * 64;
    int row_base = rg * 4;
    int tid = threadIdx.x;
    int c   = tid & 31;
    int sub = tid >> 5;

    __shared__ float xin[6][34];
    __shared__ float wsh[9][65];

    float acc[8][4];
    #pragma unroll
    for (int j = 0; j < 8; j++)
        #pragma unroll
        for (int g = 0; g < 4; g++) acc[j][g] = 0.f;

    const float* xn = x + (size_t)n * CIN * HH * WW;

    for (int ci = 0; ci < CIN; ci++) {
        if (tid < 204) {
            float s = scale[n * CIN + ci];
            int lr = tid / 34, lc = tid % 34;
            int gr = row_base - 1 + lr, gc = lc - 1;
            float v = 0.f;
            if (gr >= 0 && gr < HH && gc >= 0 && gc < WW)
                v = xn[(size_t)ci * (HH * WW) + gr * WW + gc] * s;
            xin[lr][lc] = v;
        }
        for (int idx = tid; idx < 576; idx += 256) {
            int co = idx / 9, k = idx % 9;
            wsh[k][co] = weight[(size_t)(co_base + co) * (CIN * 9) + ci * 9 + k];
        }
        __syncthreads();
        float xr[6][3];
        #pragma unroll
        for (int r = 0; r < 6; r++)
            #pragma unroll
            for (int kw = 0; kw < 3; kw++) xr[r][kw] = xin[r][c + kw];
        #pragma unroll
        for (int j = 0; j < 8; j++) {
            float wv[9];
            #pragma unroll
            for (int k = 0; k < 9; k++) wv[k] = wsh[k][sub * 8 + j];
            #pragma unroll
            for (int g = 0; g < 4; g++)
                #pragma unroll
                for (int kh = 0; kh < 3; kh++)
                    #pragma unroll
                    for (int kw = 0; kw < 3; kw++)
                        acc[j][g] += xr[g + kh][kw] * wv[kh * 3 + kw];
        }
        __syncthreads();
    }
    float gm = gmul[n];
    #pragma unroll
    for (int j = 0; j < 8; j++) {
        int co = co_base + sub * 8 + j;
        float fb = bias[co] * gm;
        #pragma unroll
        for (int g = 0; g < 4; g++)
            out[(((size_t)n * COUT + co) * HH + (row_base + g)) * WW + c] = acc[j][g] + fb;
    }
}

extern "C" void kernel_launch(void* const* d_in, const int* in_sizes, int n_in,
                              void* d_out, int out_size, void* d_ws, size_t ws_size,
                              hipStream_t stream) {
    const float* x       = (const float*)d_in[0];
    const float* weight  = (const float*)d_in[1];
    const float* bias    = (const float*)d_in[2];
    const float* tconv_w = (const float*)d_in[3];
    const float* tconv_b = (const float*)d_in[4];
    const float* fc_w    = (const float*)d_in[5];
    const float* fc_b    = (const float*)d_in[6];
    float* out = (float*)d_out;

    char* wsb = (char*)d_ws;
    float* pooled = (float*)wsb;                       // 16384 f
    float* scale  = pooled + NN * CIN;                 // 16384 f
    float* gmul   = scale + NN * CIN;                  // 64 f
    const size_t XB_OFF = 131328;                      // bytes, 16-aligned
    const size_t XB_BYTES = (size_t)NN * 32 * 34 * 34 * 8 * 2;   // 37,879,808
    const size_t WB_OFF = XB_OFF + XB_BYTES;
    const size_t WB_BYTES = (size_t)9 * 32 * COUT * 8 * 2;       // 1,179,648
    const size_t TWT_OFF = WB_OFF + WB_BYTES;
    const size_t TWT_BYTES = (size_t)3 * 256 * 256 * 4;          // 786,432
    u16* xb = (u16*)(wsb + XB_OFF);
    u16* wb = (u16*)(wsb + WB_OFF);
    float* twt = (float*)(wsb + TWT_OFF);

    if (ws_size >= TWT_OFF + TWT_BYTES) {
        xb_prep_kernel<<<NN * 32, 256, 0, stream>>>(x, pooled, xb);
        wtprep_kernel<<<512, 256, 0, stream>>>(weight, tconv_w, wb, twt);
        calib_fast_kernel<<<NN, 256, 0, stream>>>(pooled, twt, tconv_b, fc_w, fc_b, scale, gmul);
        conv_mfma_kernel<<<NN * 4 * 4, 256, 0, stream>>>(xb, wb, scale, bias, gmul, out);
    } else {
        pool_kernel<<<NN * CIN, 256, 0, stream>>>(x, pooled);
        calib_kernel<<<NN, 256, 0, stream>>>(pooled, tconv_w, tconv_b, fc_w, fc_b, scale, gmul);
        conv_kernel<<<NN * 32, 256, 0, stream>>>(x, weight, bias, scale, gmul, out);
    }
}